// Round 9
// baseline (63.608 us; speedup 1.0000x reference)
//
#include <hip/hip_runtime.h>
#include <math.h>

// Problem constants: B=8, C=128, H=W=128, HEADS=8
#define N_     16384          // H*W
#define N4     4096           // N_/4 (float4 units per row)
#define BHN    64             // B*HEADS
#define CH     16             // channels per head (hk == hv)
#define CHUNKS 64             // col chunks for k_ctx (256 cols each)

// ws layout (in floats):
//   part[64*64*256] : unnormalized partial context per (bh, chunk)   4 MB
//   zp  [64*64*16]  : unnormalized partial row-sums                256 KB
//   ctx [64*256]    : final normalized context                      64 KB
#define WS_PART 0
#define WS_ZP   (BHN * CHUNKS * 256)
#define WS_CTX  (WS_ZP + BHN * CHUNKS * 16)

typedef __attribute__((ext_vector_type(8))) short short8;   // 8 x bf16
typedef __attribute__((ext_vector_type(4))) float f32x4;

static __device__ __forceinline__ short f2bf(float f) {
    __bf16 b = (__bf16)f;                      // v_cvt f32->bf16 (RNE)
    return __builtin_bit_cast(short, b);
}

// ---------------------------------------------------------------- kernel B
// ctx_part[kk][vv] = sum_{n in strip} exp(k[kk,n]) * v[vv,n]  via bf16 MFMA.
// ONE-SHOT block (k_attend's proven structure -- the only pattern this
// session that streams >20 TB/s): burst-load the whole 16x256 tile pair
// (8 independent dwordx4 per thread), ONE barrier, compute, store, die.
// No sequential tile loop inside the block (rounds 2-8 all had one and
// all stalled at 41-56us regardless of staging mechanism).
// LDS tiles padded [16][260]: fragment ds_read_b128 of 16 rows at one
// column -> banks (4*row + col) % 32 -> rows r, r+8 collide = 2-way = free.
// Compute: wave w owns cols [64w, 64w+64) = 2 MFMA K-steps; wave partials
// cover disjoint col-slices, cross-wave sum in cred. exp applied once per
// element by its owning lane; Z accumulated in fp32 BEFORE bf16 -> exact.
__global__ __launch_bounds__(256) void k_ctx_mfma(const float* __restrict__ x1,
                                                  const float* __restrict__ x2,
                                                  float* __restrict__ ws) {
    int chunk = blockIdx.x;   // 0..63 (256-col strip)
    int bh    = blockIdx.y;   // 0..63
    int tid   = threadIdx.x;
    int w = tid >> 6, l = tid & 63;

    __shared__ float ka_s[16][260];   // x2 tile (keys), padded
    __shared__ float va_s[16][260];   // x1 tile (values), padded
    __shared__ float cred[4][256];
    __shared__ float zred[4][16];

    const float4* px2 = (const float4*)(x2 + (size_t)bh * CH * N_);
    const float4* px1 = (const float4*)(x1 + (size_t)bh * CH * N_);
    int base4 = chunk * 64;           // 256 cols = 64 float4 per row

    // burst: 8 independent loads per thread, all issued before any use
    float4 kq[4], vq[4];
    #pragma unroll
    for (int r = 0; r < 4; ++r) {
        int idx = r * 256 + tid;
        kq[r] = px2[(size_t)(idx >> 6) * N4 + base4 + (idx & 63)];
    }
    #pragma unroll
    for (int r = 0; r < 4; ++r) {
        int idx = r * 256 + tid;
        vq[r] = px1[(size_t)(idx >> 6) * N4 + base4 + (idx & 63)];
    }
    #pragma unroll
    for (int r = 0; r < 4; ++r) {
        int idx = r * 256 + tid;
        int row = idx >> 6, j = idx & 63;
        *(float4*)&ka_s[row][j * 4] = kq[r];
        *(float4*)&va_s[row][j * 4] = vq[r];
    }
    __syncthreads();

    // compute: wave w -> K-steps 2w, 2w+1 (cols 64w .. 64w+63)
    int row = l & 15;                 // kk for A, vv for B
    f32x4 acc = {0.f, 0.f, 0.f, 0.f};
    float zacc = 0.f;
    #pragma unroll
    for (int s = 0; s < 2; ++s) {
        int col = (2 * w + s) * 32 + (l >> 4) * 8;
        float4 k0 = *(const float4*)&ka_s[row][col];
        float4 k1 = *(const float4*)&ka_s[row][col + 4];
        float4 v0 = *(const float4*)&va_s[row][col];
        float4 v1 = *(const float4*)&va_s[row][col + 4];
        float e0 = __expf(k0.x), e1 = __expf(k0.y), e2 = __expf(k0.z), e3 = __expf(k0.w);
        float e4 = __expf(k1.x), e5 = __expf(k1.y), e6 = __expf(k1.z), e7 = __expf(k1.w);
        zacc += ((e0 + e1) + (e2 + e3)) + ((e4 + e5) + (e6 + e7));
        short8 af = {f2bf(e0), f2bf(e1), f2bf(e2), f2bf(e3),
                     f2bf(e4), f2bf(e5), f2bf(e6), f2bf(e7)};
        short8 bv = {f2bf(v0.x), f2bf(v0.y), f2bf(v0.z), f2bf(v0.w),
                     f2bf(v1.x), f2bf(v1.y), f2bf(v1.z), f2bf(v1.w)};
        acc = __builtin_amdgcn_mfma_f32_16x16x32_bf16(af, bv, acc, 0, 0, 0);
    }

    // Z reduce: lanes l, l^16, l^32, l^48 cover the 4 k-octets of row l&15
    zacc += __shfl_xor(zacc, 16);
    zacc += __shfl_xor(zacc, 32);
    if (l < 16) zred[w][l] = zacc;

    // ctx reduce: 4 wave partials over disjoint col-slices
    // D layout (m89-verified): lane l, reg r -> ctx[(l>>4)*4 + r][l&15]
    #pragma unroll
    for (int r = 0; r < 4; ++r)
        cred[w][((l >> 4) * 4 + r) * 16 + row] = acc[r];
    __syncthreads();

    if (tid < 16) {
        float zz = (zred[0][tid] + zred[1][tid]) + (zred[2][tid] + zred[3][tid]);
        ws[WS_ZP + (bh * CHUNKS + chunk) * 16 + tid] = zz;
    }
    float c = (cred[0][tid] + cred[1][tid]) + (cred[2][tid] + cred[3][tid]);
    ws[WS_PART + (size_t)(bh * CHUNKS + chunk) * 256 + tid] = c;   // [kk*16+vv]
}

// ---------------------------------------------------------------- kernel B2
// Collapse 64 chunk-partials -> normalized ctx[kk][vv] per bh.
__global__ __launch_bounds__(1024) void k_reduce(float* __restrict__ ws) {
    int bh  = blockIdx.x;   // 0..63
    int tid = threadIdx.x;
    int p = tid & 255, q = tid >> 8;   // output idx, chunk quarter

    float s = 0.f;
    #pragma unroll
    for (int c = q; c < CHUNKS; c += 4)
        s += ws[WS_PART + (size_t)(bh * CHUNKS + c) * 256 + p];

    __shared__ float red[4][256];
    __shared__ float zpart[4][16];
    red[q][p] = s;
    if (p < 16) {
        float z = 0.f;
        #pragma unroll
        for (int c = q; c < CHUNKS; c += 4)
            z += ws[WS_ZP + (bh * CHUNKS + c) * 16 + p];
        zpart[q][p] = z;
    }
    __syncthreads();

    if (tid < 256) {
        float tot = (red[0][p] + red[1][p]) + (red[2][p] + red[3][p]);
        int kk = p >> 4;
        float zz = (zpart[0][kk] + zpart[1][kk]) + (zpart[2][kk] + zpart[3][kk]);
        ws[WS_CTX + bh * 256 + p] = tot / zz;
    }
}

// ---------------------------------------------------------------- kernel C
// Per (bh, 256-col block):
//   phase A : channel softmax of x2 columns (16 channels)
//   phase B : out[vv][n] = sum_kk ctx[kk][vv] * qsm[kk][n]
__global__ __launch_bounds__(256) void k_attend(const float* __restrict__ x2,
                                                const float* __restrict__ ws,
                                                float* __restrict__ out) {
    int cb  = blockIdx.x;   // 0..63 column block (256 cols)
    int bh  = blockIdx.y;   // 0..63
    int tid = threadIdx.x;

    __shared__ float q_s[16][256];   // k tile, then (in-place) qsm tile
    __shared__ float ctxs[256];

    ctxs[tid] = ws[WS_CTX + bh * 256 + tid];   // normalized ctx (L2-hot)

    const float4* px = (const float4*)(x2 + (size_t)bh * CH * N_);
    int base4 = cb * 64;             // 256 cols = 64 float4 per row
    #pragma unroll
    for (int r = 0; r < 4; ++r) {
        int idx = r * 256 + tid;
        int ch = idx >> 6, j = idx & 63;
        float4 v = px[(size_t)ch * N4 + base4 + j];
        *(float4*)&q_s[ch][j * 4] = v;
    }
    __syncthreads();

    // phase A: thread = column; softmax over 16 channels, in place
    {
        int col = tid;
        float kv[16];
        #pragma unroll
        for (int c = 0; c < 16; ++c) kv[c] = q_s[c][col];
        float mx = kv[0];
        #pragma unroll
        for (int c = 1; c < 16; ++c) mx = fmaxf(mx, kv[c]);
        float s = 0.f;
        #pragma unroll
        for (int c = 0; c < 16; ++c) { kv[c] = __expf(kv[c] - mx); s += kv[c]; }
        float rs = 1.0f / s;
        #pragma unroll
        for (int c = 0; c < 16; ++c) q_s[c][col] = kv[c] * rs;
    }
    __syncthreads();

    // phase B: thread = (vg, cq); 4 vv x 4 cols register block
    int vg = tid >> 6, cq = tid & 63;
    int vv0 = vg * 4, c0 = cq * 4;
    float4 a0 = make_float4(0.f,0.f,0.f,0.f);
    float4 a1 = a0, a2 = a0, a3 = a0;   // a{c}[v]: col c, 4 vv's
    #pragma unroll
    for (int kk = 0; kk < 16; ++kk) {
        float4 cx = *(const float4*)&ctxs[kk * 16 + vv0];   // wave-uniform -> broadcast
        float4 q4 = *(const float4*)&q_s[kk][c0];
        a0.x = fmaf(q4.x, cx.x, a0.x); a0.y = fmaf(q4.x, cx.y, a0.y);
        a0.z = fmaf(q4.x, cx.z, a0.z); a0.w = fmaf(q4.x, cx.w, a0.w);
        a1.x = fmaf(q4.y, cx.x, a1.x); a1.y = fmaf(q4.y, cx.y, a1.y);
        a1.z = fmaf(q4.y, cx.z, a1.z); a1.w = fmaf(q4.y, cx.w, a1.w);
        a2.x = fmaf(q4.z, cx.x, a2.x); a2.y = fmaf(q4.z, cx.y, a2.y);
        a2.z = fmaf(q4.z, cx.z, a2.z); a2.w = fmaf(q4.z, cx.w, a2.w);
        a3.x = fmaf(q4.w, cx.x, a3.x); a3.y = fmaf(q4.w, cx.y, a3.y);
        a3.z = fmaf(q4.w, cx.z, a3.z); a3.w = fmaf(q4.w, cx.w, a3.w);
    }
    size_t outbase = (size_t)bh * CH * N_ + (size_t)cb * 256 + c0;
    float4 o;
    o = make_float4(a0.x, a1.x, a2.x, a3.x);
    *(float4*)&out[outbase + (size_t)(vv0 + 0) * N_] = o;
    o = make_float4(a0.y, a1.y, a2.y, a3.y);
    *(float4*)&out[outbase + (size_t)(vv0 + 1) * N_] = o;
    o = make_float4(a0.z, a1.z, a2.z, a3.z);
    *(float4*)&out[outbase + (size_t)(vv0 + 2) * N_] = o;
    o = make_float4(a0.w, a1.w, a2.w, a3.w);
    *(float4*)&out[outbase + (size_t)(vv0 + 3) * N_] = o;
}

// ---------------------------------------------------------------- launch
extern "C" void kernel_launch(void* const* d_in, const int* in_sizes, int n_in,
                              void* d_out, int out_size, void* d_ws, size_t ws_size,
                              hipStream_t stream) {
    const float* x1 = (const float*)d_in[0];   // values
    const float* x2 = (const float*)d_in[1];   // keys / queries
    float* out = (float*)d_out;
    float* ws  = (float*)d_ws;

    k_ctx_mfma <<<dim3(CHUNKS, BHN), 256,  0, stream>>>(x1, x2, ws);
    k_reduce   <<<BHN,               1024, 0, stream>>>(ws);
    k_attend   <<<dim3(64, BHN),     256,  0, stream>>>(x2, ws, out);
}

// Round 10
// 52.500 us; speedup vs baseline: 1.2116x; 1.2116x over previous
//
#include <hip/hip_runtime.h>
#include <math.h>

// Problem constants: B=8, C=128, H=W=128, HEADS=8
#define N_     16384          // H*W
#define N4     4096           // N_/4 (float4 units per row)
#define BHN    64             // B*HEADS
#define CH     16             // channels per head (hk == hv)
#define CHUNKS 64             // col chunks for k_ctx (256 cols each)

// ws layout (in floats):
//   part[64*64*256] : unnormalized partial context per (bh, chunk)   4 MB
//   zp  [64*64*16]  : unnormalized partial row-sums                256 KB
//   q   [64*4*256]  : quarter-reduced context                      256 KB
//   zq  [64*4*16]   : quarter-reduced Z                             16 KB
#define WS_PART 0
#define WS_ZP   (BHN * CHUNKS * 256)
#define WS_Q    (WS_ZP + BHN * CHUNKS * 16)
#define WS_ZQ   (WS_Q + BHN * 4 * 256)

typedef __attribute__((ext_vector_type(8))) short short8;   // 8 x bf16
typedef __attribute__((ext_vector_type(4))) float f32x4;

static __device__ __forceinline__ short f2bf(float f) {
    __bf16 b = (__bf16)f;                      // v_cvt f32->bf16 (RNE)
    return __builtin_bit_cast(short, b);
}

// ---------------------------------------------------------------- kernel B
// ctx_part[kk][vv] = sum_{n in strip} exp(k[kk,n]) * v[vv,n]  via bf16 MFMA.
// One-shot block (round-9 structure).
// NEW (decongruence test): across r2-r9, EVERY k_ctx variant streaming
// x1+x2 at congruent addresses (same offset in two 64MB regions, 2^26
// apart -> identical cache index/bank bits) capped at 1.4-1.7 TB/s fetch,
// while single-array kernels (k_rowstats, k_attend) hit 5-10 TB/s on the
// same access shape. Fix: the thread that loads x2(row,col) loads
// x1((row+8)&15,(col+32)&63) -> simultaneous request pairs differ by
// ~512KB+512B (bits 9,19 flip) instead of exactly 2^26. Content still
// lands at its canonical LDS slot; compute unchanged.
__global__ __launch_bounds__(256) void k_ctx_mfma(const float* __restrict__ x1,
                                                  const float* __restrict__ x2,
                                                  float* __restrict__ ws) {
    int chunk = blockIdx.x;   // 0..63 (256-col strip)
    int bh    = blockIdx.y;   // 0..63
    int tid   = threadIdx.x;
    int w = tid >> 6, l = tid & 63;

    __shared__ float ka_s[16][260];   // x2 tile (keys), padded
    __shared__ float va_s[16][260];   // x1 tile (values), padded
    __shared__ float cred[4][256];
    __shared__ float zred[4][16];

    const float4* px2 = (const float4*)(x2 + (size_t)bh * CH * N_);
    const float4* px1 = (const float4*)(x1 + (size_t)bh * CH * N_);
    int base4 = chunk * 64;           // 256 cols = 64 float4 per row

    // burst: 8 independent loads per thread, all issued before any use
    float4 kq[4], vq[4];
    #pragma unroll
    for (int r = 0; r < 4; ++r) {
        int idx = r * 256 + tid;
        kq[r] = px2[(size_t)(idx >> 6) * N4 + base4 + (idx & 63)];
    }
    #pragma unroll
    for (int r = 0; r < 4; ++r) {
        int idx = r * 256 + tid;
        int row2 = ((idx >> 6) + 8) & 15;      // rotated assignment
        int j2   = ((idx & 63) + 32) & 63;
        vq[r] = px1[(size_t)row2 * N4 + base4 + j2];
    }
    #pragma unroll
    for (int r = 0; r < 4; ++r) {
        int idx = r * 256 + tid;
        int row = idx >> 6, j = idx & 63;
        *(float4*)&ka_s[row][j * 4] = kq[r];
        int row2 = (row + 8) & 15, j2 = (j + 32) & 63;
        *(float4*)&va_s[row2][j2 * 4] = vq[r];   // canonical slot
    }
    __syncthreads();

    // compute: wave w -> K-steps 2w, 2w+1 (cols 64w .. 64w+63)
    int row = l & 15;                 // kk for A, vv for B
    f32x4 acc = {0.f, 0.f, 0.f, 0.f};
    float zacc = 0.f;
    #pragma unroll
    for (int s = 0; s < 2; ++s) {
        int col = (2 * w + s) * 32 + (l >> 4) * 8;
        float4 k0 = *(const float4*)&ka_s[row][col];
        float4 k1 = *(const float4*)&ka_s[row][col + 4];
        float4 v0 = *(const float4*)&va_s[row][col];
        float4 v1 = *(const float4*)&va_s[row][col + 4];
        float e0 = __expf(k0.x), e1 = __expf(k0.y), e2 = __expf(k0.z), e3 = __expf(k0.w);
        float e4 = __expf(k1.x), e5 = __expf(k1.y), e6 = __expf(k1.z), e7 = __expf(k1.w);
        zacc += ((e0 + e1) + (e2 + e3)) + ((e4 + e5) + (e6 + e7));
        short8 af = {f2bf(e0), f2bf(e1), f2bf(e2), f2bf(e3),
                     f2bf(e4), f2bf(e5), f2bf(e6), f2bf(e7)};
        short8 bv = {f2bf(v0.x), f2bf(v0.y), f2bf(v0.z), f2bf(v0.w),
                     f2bf(v1.x), f2bf(v1.y), f2bf(v1.z), f2bf(v1.w)};
        acc = __builtin_amdgcn_mfma_f32_16x16x32_bf16(af, bv, acc, 0, 0, 0);
    }

    // Z reduce: lanes l, l^16, l^32, l^48 cover the 4 k-octets of row l&15
    zacc += __shfl_xor(zacc, 16);
    zacc += __shfl_xor(zacc, 32);
    if (l < 16) zred[w][l] = zacc;

    // ctx reduce: 4 wave partials over disjoint col-slices
    // D layout (m89-verified): lane l, reg r -> ctx[(l>>4)*4 + r][l&15]
    #pragma unroll
    for (int r = 0; r < 4; ++r)
        cred[w][((l >> 4) * 4 + r) * 16 + row] = acc[r];
    __syncthreads();

    if (tid < 16) {
        float zz = (zred[0][tid] + zred[1][tid]) + (zred[2][tid] + zred[3][tid]);
        ws[WS_ZP + (bh * CHUNKS + chunk) * 16 + tid] = zz;
    }
    float c = (cred[0][tid] + cred[1][tid]) + (cred[2][tid] + cred[3][tid]);
    ws[WS_PART + (size_t)(bh * CHUNKS + chunk) * 256 + tid] = c;   // [kk*16+vv]
}

// ---------------------------------------------------------------- kernel B2
// Quarter-reduce: 256 blocks (bh, quarter q), each sums 16 chunk-partials.
// (Round-9's 64-block version used 1/4 of the chip and was latency-bound.)
__global__ __launch_bounds__(256) void k_reduce(float* __restrict__ ws) {
    int bq  = blockIdx.x;   // 0..255
    int bh  = bq >> 2, q = bq & 3;
    int tid = threadIdx.x;

    float s = 0.f;
    #pragma unroll
    for (int c = q * 16; c < q * 16 + 16; ++c)
        s += ws[WS_PART + (size_t)(bh * CHUNKS + c) * 256 + tid];
    ws[WS_Q + (bh * 4 + q) * 256 + tid] = s;

    if (tid < 16) {
        float z = 0.f;
        #pragma unroll
        for (int c = q * 16; c < q * 16 + 16; ++c)
            z += ws[WS_ZP + (bh * CHUNKS + c) * 16 + tid];
        ws[WS_ZQ + (bh * 4 + q) * 16 + tid] = z;
    }
}

// ---------------------------------------------------------------- kernel C
// Per (bh, 256-col block):
//   prologue: sum 4 quarter-partials -> ctx[kk][vv] (normalized by Z[kk])
//   phase A : channel softmax of x2 columns (16 channels)
//   phase B : out[vv][n] = sum_kk ctx[kk][vv] * qsm[kk][n]
__global__ __launch_bounds__(256) void k_attend(const float* __restrict__ x2,
                                                const float* __restrict__ ws,
                                                float* __restrict__ out) {
    int cb  = blockIdx.x;   // 0..63 column block (256 cols)
    int bh  = blockIdx.y;   // 0..63
    int tid = threadIdx.x;

    __shared__ float q_s[16][256];   // k tile, then (in-place) qsm tile
    __shared__ float ctxs[256];
    __shared__ float rzs[16];

    float csum = (ws[WS_Q + (bh * 4 + 0) * 256 + tid]
                + ws[WS_Q + (bh * 4 + 1) * 256 + tid])
               + (ws[WS_Q + (bh * 4 + 2) * 256 + tid]
                + ws[WS_Q + (bh * 4 + 3) * 256 + tid]);
    if (tid < 16) {
        float z = (ws[WS_ZQ + (bh * 4 + 0) * 16 + tid]
                 + ws[WS_ZQ + (bh * 4 + 1) * 16 + tid])
                + (ws[WS_ZQ + (bh * 4 + 2) * 16 + tid]
                 + ws[WS_ZQ + (bh * 4 + 3) * 16 + tid]);
        rzs[tid] = 1.0f / z;
    }

    const float4* px = (const float4*)(x2 + (size_t)bh * CH * N_);
    int base4 = cb * 64;             // 256 cols = 64 float4 per row
    #pragma unroll
    for (int r = 0; r < 4; ++r) {
        int idx = r * 256 + tid;
        int ch = idx >> 6, j = idx & 63;
        float4 v = px[(size_t)ch * N4 + base4 + j];
        *(float4*)&q_s[ch][j * 4] = v;
    }
    __syncthreads();

    ctxs[tid] = csum * rzs[tid >> 4];   // ctx[kk][vv], kk = tid>>4

    // phase A: thread = column; softmax over 16 channels, in place
    {
        int col = tid;
        float kv[16];
        #pragma unroll
        for (int c = 0; c < 16; ++c) kv[c] = q_s[c][col];
        float mx = kv[0];
        #pragma unroll
        for (int c = 1; c < 16; ++c) mx = fmaxf(mx, kv[c]);
        float s = 0.f;
        #pragma unroll
        for (int c = 0; c < 16; ++c) { kv[c] = __expf(kv[c] - mx); s += kv[c]; }
        float rs = 1.0f / s;
        #pragma unroll
        for (int c = 0; c < 16; ++c) q_s[c][col] = kv[c] * rs;
    }
    __syncthreads();

    // phase B: thread = (vg, cq); 4 vv x 4 cols register block
    int vg = tid >> 6, cq = tid & 63;
    int vv0 = vg * 4, c0 = cq * 4;
    float4 a0 = make_float4(0.f,0.f,0.f,0.f);
    float4 a1 = a0, a2 = a0, a3 = a0;   // a{c}[v]: col c, 4 vv's
    #pragma unroll
    for (int kk = 0; kk < 16; ++kk) {
        float4 cx = *(const float4*)&ctxs[kk * 16 + vv0];   // wave-uniform -> broadcast
        float4 q4 = *(const float4*)&q_s[kk][c0];
        a0.x = fmaf(q4.x, cx.x, a0.x); a0.y = fmaf(q4.x, cx.y, a0.y);
        a0.z = fmaf(q4.x, cx.z, a0.z); a0.w = fmaf(q4.x, cx.w, a0.w);
        a1.x = fmaf(q4.y, cx.x, a1.x); a1.y = fmaf(q4.y, cx.y, a1.y);
        a1.z = fmaf(q4.y, cx.z, a1.z); a1.w = fmaf(q4.y, cx.w, a1.w);
        a2.x = fmaf(q4.z, cx.x, a2.x); a2.y = fmaf(q4.z, cx.y, a2.y);
        a2.z = fmaf(q4.z, cx.z, a2.z); a2.w = fmaf(q4.z, cx.w, a2.w);
        a3.x = fmaf(q4.w, cx.x, a3.x); a3.y = fmaf(q4.w, cx.y, a3.y);
        a3.z = fmaf(q4.w, cx.z, a3.z); a3.w = fmaf(q4.w, cx.w, a3.w);
    }
    size_t outbase = (size_t)bh * CH * N_ + (size_t)cb * 256 + c0;
    float4 o;
    o = make_float4(a0.x, a1.x, a2.x, a3.x);
    *(float4*)&out[outbase + (size_t)(vv0 + 0) * N_] = o;
    o = make_float4(a0.y, a1.y, a2.y, a3.y);
    *(float4*)&out[outbase + (size_t)(vv0 + 1) * N_] = o;
    o = make_float4(a0.z, a1.z, a2.z, a3.z);
    *(float4*)&out[outbase + (size_t)(vv0 + 2) * N_] = o;
    o = make_float4(a0.w, a1.w, a2.w, a3.w);
    *(float4*)&out[outbase + (size_t)(vv0 + 3) * N_] = o;
}

// ---------------------------------------------------------------- launch
extern "C" void kernel_launch(void* const* d_in, const int* in_sizes, int n_in,
                              void* d_out, int out_size, void* d_ws, size_t ws_size,
                              hipStream_t stream) {
    const float* x1 = (const float*)d_in[0];   // values
    const float* x2 = (const float*)d_in[1];   // keys / queries
    float* out = (float*)d_out;
    float* ws  = (float*)d_ws;

    k_ctx_mfma <<<dim3(CHUNKS, BHN), 256, 0, stream>>>(x1, x2, ws);
    k_reduce   <<<BHN * 4,           256, 0, stream>>>(ws);
    k_attend   <<<dim3(64, BHN),     256, 0, stream>>>(x2, ws, out);
}

// Round 11
// 52.025 us; speedup vs baseline: 1.2226x; 1.0091x over previous
//
#include <hip/hip_runtime.h>
#include <math.h>

// Problem constants: B=8, C=128, H=W=128, HEADS=8
#define N_     16384          // H*W
#define N4     4096           // N_/4 (float4 units per row)
#define BHN    64             // B*HEADS
#define CH     16             // channels per head (hk == hv)
#define CHUNKS 16             // col chunks for k_ctx (1024 cols each)

// ws layout (in floats):
//   part[64*16*256] : unnormalized partial context per (bh, chunk)
//   zp  [64*16*16]  : unnormalized partial row-sums per (bh, chunk, kk)
#define WS_PART 0
#define WS_ZP   (BHN * CHUNKS * 256)

typedef __attribute__((ext_vector_type(8))) short short8;   // 8 x bf16
typedef __attribute__((ext_vector_type(4))) float f32x4;

static __device__ __forceinline__ short f2bf(float f) {
    __bf16 b = (__bf16)f;                      // v_cvt f32->bf16 (RNE)
    return __builtin_bit_cast(short, b);
}

// ---------------------------------------------------------------- kernel B
// ctx_part[kk][vv] = sum_{n in strip} exp(k[kk,n]) * v[vv,n]  via bf16 MFMA.
// ROW-CONTIGUOUS STAGING (the change under test): rounds 2-10 all read
// 16-rows-by-1KB tiles (64KB row stride) and ALL capped at ~1.65 TB/s HBM
// no matter the schedule; the only >5 TB/s readers this session streamed
// rows sequentially (k_rowstats r1). So: wave w streams rows 4w..4w+3 of
// x2 (4 back-to-back 1KB-coalesced float4 loads per row = 4KB sequential,
// 2-deep row prefetch), applies exp (fp32 Z per row BEFORE bf16 rounding),
// writes bf16 to LDS; then rows 4w..4w+3 of x1. One barrier. MFMA tiles
// are formed from LDS, where the 16-rows-at-same-n shape is free.
// Compute: wave w owns cols [256w, 256w+256) = 8 K=32 MFMA steps; wave
// partials cover disjoint col-slices, cross-wave sum in cred.
// LDS tiles [16][1032] bf16: row stride 2064B = 516 words; fragment
// ds_read_b128 banks = 4*((row+q)&7)+{0..3} -> all 32 banks, ~free.
__global__ __launch_bounds__(256) void k_ctx_mfma(const float* __restrict__ x1,
                                                  const float* __restrict__ x2,
                                                  float* __restrict__ ws) {
    int chunk = blockIdx.x;   // 0..15 (1024-col strip)
    int bh    = blockIdx.y;   // 0..63
    int tid   = threadIdx.x;
    int w = tid >> 6, l = tid & 63;

    __shared__ __align__(16) short e_s[16][1032];   // exp'd keys, bf16
    __shared__ __align__(16) short v_s[16][1032];   // values, bf16
    __shared__ float cred[4][256];
    __shared__ float zs[16];

    const float* xb2 = x2 + (size_t)bh * CH * N_ + chunk * 1024;
    const float* xb1 = x1 + (size_t)bh * CH * N_ + chunk * 1024;

    // ---- stage x2 rows 4w..4w+3: sequential 4KB stream per wave
    {
        int row = 4 * w;
        const float4* src = (const float4*)(xb2 + (size_t)row * N_);
        float4 a0 = src[l], a1 = src[64 + l], a2 = src[128 + l], a3 = src[192 + l];
        #pragma unroll
        for (int rr = 0; rr < 4; ++rr) {
            float4 b0 = a0, b1 = a1, b2 = a2, b3 = a3;
            if (rr < 3) {   // prefetch next row while processing this one
                const float4* nx = (const float4*)(xb2 + (size_t)(row + rr + 1) * N_);
                a0 = nx[l]; a1 = nx[64 + l]; a2 = nx[128 + l]; a3 = nx[192 + l];
            }
            int r = row + rr;
            float e[16];
            e[0]=__expf(b0.x); e[1]=__expf(b0.y); e[2]=__expf(b0.z); e[3]=__expf(b0.w);
            e[4]=__expf(b1.x); e[5]=__expf(b1.y); e[6]=__expf(b1.z); e[7]=__expf(b1.w);
            e[8]=__expf(b2.x); e[9]=__expf(b2.y); e[10]=__expf(b2.z); e[11]=__expf(b2.w);
            e[12]=__expf(b3.x); e[13]=__expf(b3.y); e[14]=__expf(b3.z); e[15]=__expf(b3.w);
            float z = 0.f;
            #pragma unroll
            for (int i = 0; i < 16; ++i) z += e[i];
            #pragma unroll
            for (int off = 1; off < 64; off <<= 1) z += __shfl_xor(z, off);
            if (l == 0) zs[r] = z;
            #pragma unroll
            for (int s = 0; s < 4; ++s) {
                short4 pk = make_short4(f2bf(e[s*4]), f2bf(e[s*4+1]),
                                        f2bf(e[s*4+2]), f2bf(e[s*4+3]));
                *(short4*)&e_s[r][s * 256 + l * 4] = pk;
            }
        }
    }
    // ---- stage x1 rows 4w..4w+3 (values: no exp, no Z)
    {
        int row = 4 * w;
        const float4* src = (const float4*)(xb1 + (size_t)row * N_);
        float4 a0 = src[l], a1 = src[64 + l], a2 = src[128 + l], a3 = src[192 + l];
        #pragma unroll
        for (int rr = 0; rr < 4; ++rr) {
            float4 b0 = a0, b1 = a1, b2 = a2, b3 = a3;
            if (rr < 3) {
                const float4* nx = (const float4*)(xb1 + (size_t)(row + rr + 1) * N_);
                a0 = nx[l]; a1 = nx[64 + l]; a2 = nx[128 + l]; a3 = nx[192 + l];
            }
            int r = row + rr;
            *(short4*)&v_s[r][0 * 256 + l * 4] = make_short4(f2bf(b0.x), f2bf(b0.y), f2bf(b0.z), f2bf(b0.w));
            *(short4*)&v_s[r][1 * 256 + l * 4] = make_short4(f2bf(b1.x), f2bf(b1.y), f2bf(b1.z), f2bf(b1.w));
            *(short4*)&v_s[r][2 * 256 + l * 4] = make_short4(f2bf(b2.x), f2bf(b2.y), f2bf(b2.z), f2bf(b2.w));
            *(short4*)&v_s[r][3 * 256 + l * 4] = make_short4(f2bf(b3.x), f2bf(b3.y), f2bf(b3.z), f2bf(b3.w));
        }
    }
    __syncthreads();

    // ---- compute: wave w -> cols [256w, 256w+256) = 8 K=32 MFMA steps
    int row16 = l & 15;               // kk for A, vv for B
    int q     = l >> 4;               // k-octet within K=32
    f32x4 acc = {0.f, 0.f, 0.f, 0.f};
    #pragma unroll
    for (int s = 0; s < 8; ++s) {
        int col = w * 256 + s * 32 + q * 8;
        short8 af = *(const short8*)&e_s[row16][col];
        short8 bv = *(const short8*)&v_s[row16][col];
        acc = __builtin_amdgcn_mfma_f32_16x16x32_bf16(af, bv, acc, 0, 0, 0);
    }

    // ---- ctx reduce: 4 wave partials over disjoint col-slices
    // D layout (m89-verified): lane l, reg r -> ctx[(l>>4)*4 + r][l&15]
    #pragma unroll
    for (int r = 0; r < 4; ++r)
        cred[w][(q * 4 + r) * 16 + row16] = acc[r];
    __syncthreads();

    if (tid < 16)
        ws[WS_ZP + (bh * CHUNKS + chunk) * 16 + tid] = zs[tid];
    float c = (cred[0][tid] + cred[1][tid]) + (cred[2][tid] + cred[3][tid]);
    ws[WS_PART + (size_t)(bh * CHUNKS + chunk) * 256 + tid] = c;   // [kk*16+vv]
}

// ---------------------------------------------------------------- kernel C
// Per (bh, 256-col block):
//   prologue: reduce 16 chunk-partials -> ctx[kk][vv] (normalized by Z[kk])
//   phase A : channel softmax of x2 columns (16 channels)
//   phase B : out[vv][n] = sum_kk ctx[kk][vv] * qsm[kk][n]
__global__ __launch_bounds__(256) void k_attend(const float* __restrict__ x2,
                                                const float* __restrict__ ws,
                                                float* __restrict__ out) {
    int cb  = blockIdx.x;   // 0..63 column block (256 cols)
    int bh  = blockIdx.y;   // 0..63
    int tid = threadIdx.x;

    __shared__ float q_s[16][256];   // k tile, then (in-place) qsm tile
    __shared__ float ctxs[256];
    __shared__ float rzs[16];

    // reduce partial context (L2/L3 hits; overlaps with tile load)
    float csum = 0.f;
    #pragma unroll
    for (int c = 0; c < CHUNKS; ++c)
        csum += ws[WS_PART + (size_t)(bh * CHUNKS + c) * 256 + tid];
    if (tid < 16) {
        float z = 0.f;
        #pragma unroll
        for (int c = 0; c < CHUNKS; ++c)
            z += ws[WS_ZP + (bh * CHUNKS + c) * 16 + tid];
        rzs[tid] = 1.0f / z;
    }

    const float4* px = (const float4*)(x2 + (size_t)bh * CH * N_);
    int base4 = cb * 64;             // 256 cols = 64 float4 per row
    #pragma unroll
    for (int r = 0; r < 4; ++r) {
        int idx = r * 256 + tid;
        int ch = idx >> 6, j = idx & 63;
        float4 v = px[(size_t)ch * N4 + base4 + j];
        *(float4*)&q_s[ch][j * 4] = v;
    }
    __syncthreads();

    ctxs[tid] = csum * rzs[tid >> 4];   // ctx[kk][vv], kk = tid>>4

    // phase A: thread = column; softmax over 16 channels, in place
    {
        int col = tid;
        float kv[16];
        #pragma unroll
        for (int c = 0; c < 16; ++c) kv[c] = q_s[c][col];
        float mx = kv[0];
        #pragma unroll
        for (int c = 1; c < 16; ++c) mx = fmaxf(mx, kv[c]);
        float s = 0.f;
        #pragma unroll
        for (int c = 0; c < 16; ++c) { kv[c] = __expf(kv[c] - mx); s += kv[c]; }
        float rs = 1.0f / s;
        #pragma unroll
        for (int c = 0; c < 16; ++c) q_s[c][col] = kv[c] * rs;
    }
    __syncthreads();

    // phase B: thread = (vg, cq); 4 vv x 4 cols register block
    int vg = tid >> 6, cq = tid & 63;
    int vv0 = vg * 4, c0 = cq * 4;
    float4 a0 = make_float4(0.f,0.f,0.f,0.f);
    float4 a1 = a0, a2 = a0, a3 = a0;   // a{c}[v]: col c, 4 vv's
    #pragma unroll
    for (int kk = 0; kk < 16; ++kk) {
        float4 cx = *(const float4*)&ctxs[kk * 16 + vv0];   // wave-uniform -> broadcast
        float4 q4 = *(const float4*)&q_s[kk][c0];
        a0.x = fmaf(q4.x, cx.x, a0.x); a0.y = fmaf(q4.x, cx.y, a0.y);
        a0.z = fmaf(q4.x, cx.z, a0.z); a0.w = fmaf(q4.x, cx.w, a0.w);
        a1.x = fmaf(q4.y, cx.x, a1.x); a1.y = fmaf(q4.y, cx.y, a1.y);
        a1.z = fmaf(q4.y, cx.z, a1.z); a1.w = fmaf(q4.y, cx.w, a1.w);
        a2.x = fmaf(q4.z, cx.x, a2.x); a2.y = fmaf(q4.z, cx.y, a2.y);
        a2.z = fmaf(q4.z, cx.z, a2.z); a2.w = fmaf(q4.z, cx.w, a2.w);
        a3.x = fmaf(q4.w, cx.x, a3.x); a3.y = fmaf(q4.w, cx.y, a3.y);
        a3.z = fmaf(q4.w, cx.z, a3.z); a3.w = fmaf(q4.w, cx.w, a3.w);
    }
    size_t outbase = (size_t)bh * CH * N_ + (size_t)cb * 256 + c0;
    float4 o;
    o = make_float4(a0.x, a1.x, a2.x, a3.x);
    *(float4*)&out[outbase + (size_t)(vv0 + 0) * N_] = o;
    o = make_float4(a0.y, a1.y, a2.y, a3.y);
    *(float4*)&out[outbase + (size_t)(vv0 + 1) * N_] = o;
    o = make_float4(a0.z, a1.z, a2.z, a3.z);
    *(float4*)&out[outbase + (size_t)(vv0 + 2) * N_] = o;
    o = make_float4(a0.w, a1.w, a2.w, a3.w);
    *(float4*)&out[outbase + (size_t)(vv0 + 3) * N_] = o;
}

// ---------------------------------------------------------------- launch
extern "C" void kernel_launch(void* const* d_in, const int* in_sizes, int n_in,
                              void* d_out, int out_size, void* d_ws, size_t ws_size,
                              hipStream_t stream) {
    const float* x1 = (const float*)d_in[0];   // values
    const float* x2 = (const float*)d_in[1];   // keys / queries
    float* out = (float*)d_out;
    float* ws  = (float*)d_ws;

    k_ctx_mfma <<<dim3(CHUNKS, BHN), 256, 0, stream>>>(x1, x2, ws);
    k_attend   <<<dim3(64, BHN),     256, 0, stream>>>(x2, ws, out);
}